// Round 2
// baseline (36.621 us; speedup 1.0000x reference)
//
#include <hip/hip_runtime.h>
#include <math.h>

// CenterLoss reduces to: for each row b, d_b = clip(1 - cos(f_b, c_{t_b}), EPS, MAXV);
// loss = mean_b(d_b) + (C-1)*EPS   (clip floors all masked-out zeros at EPS).
//
// Single fused kernel: 1024 blocks x 256 thr (1 wave = 1 row). Each block
// accumulates its 4-row partial into a fixed-point u64 device atomic
// (order-independent -> bit-deterministic), then the last-arriving block
// (ticket counter) converts and writes the scalar loss. A 16 B memset node
// re-zeros {acc, ticket} at the start of every replay.

#define BATCH_N 4096
#define EMBED_N 512
#define NUM_CLASSES_N 10000
#define EPS_F 1e-12f
#define MAXV_F 1e12f

#define FP_SCALE 17592186044416.0   // 2^44
#define INV_FP_SCALE (1.0 / 17592186044416.0)

__global__ __launch_bounds__(256) void center_loss_fused(
    const float* __restrict__ features,   // (B, 512)
    const float* __restrict__ centers,    // (C, 512)
    const int*   __restrict__ targets,    // (B,)
    unsigned long long* __restrict__ acc, // fixed-point sum accumulator
    unsigned*    __restrict__ ticket,     // block-completion counter
    float*       __restrict__ out)        // scalar loss
{
    const int wave = threadIdx.x >> 6;       // 0..3
    const int lane = threadIdx.x & 63;
    const int b = blockIdx.x * 4 + wave;     // grid is exactly B/4 blocks

    const int t = targets[b];
    const float4* f4 = (const float4*)(features + (size_t)b * EMBED_N);
    const float4* c4 = (const float4*)(centers  + (size_t)t * EMBED_N);

    float dot = 0.f, ff = 0.f, cc = 0.f;
    // 512 floats = 128 float4; 64 lanes x 2 iters, lane-consecutive (coalesced).
    #pragma unroll
    for (int k = 0; k < 2; ++k) {
        const float4 fv = f4[lane + 64 * k];
        const float4 cv = c4[lane + 64 * k];
        dot += fv.x * cv.x + fv.y * cv.y + fv.z * cv.z + fv.w * cv.w;
        ff  += fv.x * fv.x + fv.y * fv.y + fv.z * fv.z + fv.w * fv.w;
        cc  += cv.x * cv.x + cv.y * cv.y + cv.z * cv.z + cv.w * cv.w;
    }

    #pragma unroll
    for (int off = 32; off >= 1; off >>= 1) {
        dot += __shfl_xor(dot, off, 64);
        ff  += __shfl_xor(ff,  off, 64);
        cc  += __shfl_xor(cc,  off, 64);
    }

    __shared__ float sd[4];
    if (lane == 0) {
        float d = 1.0f - dot / (sqrtf(ff) * sqrtf(cc));
        sd[wave] = fminf(fmaxf(d, EPS_F), MAXV_F);
    }
    __syncthreads();

    if (threadIdx.x == 0) {
        const float bs = sd[0] + sd[1] + sd[2] + sd[3];          // <= 8.0
        const unsigned long long q =
            (unsigned long long)((double)bs * FP_SCALE);          // <= 2^47
        atomicAdd(acc, q);                                        // device-scope
        __threadfence();                                          // acc-add before ticket-add
        const unsigned old = atomicAdd(ticket, 1u);
        if (old == gridDim.x - 1) {                               // last block
            __threadfence();
            const unsigned long long tot = atomicAdd(acc, 0ull);  // coherent read
            out[0] = (float)((double)tot * INV_FP_SCALE * (1.0 / BATCH_N)
                             + (double)(NUM_CLASSES_N - 1) * 1e-12);
        }
    }
}

extern "C" void kernel_launch(void* const* d_in, const int* in_sizes, int n_in,
                              void* d_out, int out_size, void* d_ws, size_t ws_size,
                              hipStream_t stream) {
    const float* features = (const float*)d_in[0];
    const float* centers  = (const float*)d_in[1];
    const int*   targets  = (const int*)d_in[2];
    float* out = (float*)d_out;

    unsigned long long* acc = (unsigned long long*)d_ws;      // 8 B
    unsigned* ticket = (unsigned*)((char*)d_ws + 8);          // 4 B

    hipMemsetAsync(d_ws, 0, 16, stream);                      // zero acc + ticket
    center_loss_fused<<<BATCH_N / 4, 256, 0, stream>>>(
        features, centers, targets, acc, ticket, out);
}